// Round 7
// baseline (1045.244 us; speedup 1.0000x reference)
//
#include <hip/hip_runtime.h>
#include <stdint.h>

// Keep mul+add sequences UNFUSED so we bit-match XLA:CPU's unfused MulAdd ops.
#pragma clang fp contract(off)

#define BE_C     256
#define N_C      4096
#define K_C      32
#define NEG_C    (-1e30f)
#define OUT_HALF 1048576

// ---------------- XLA:CPU exp, trimmed for x <= 0 (bit-exact identities) ----------------
__device__ __forceinline__ float xla_exp_neg(float x) {
  const float exp_lo = -88.3762626647949f;
  const float log2ef = 1.44269504088896341f;
  const float c1 = 0.693359375f;
  const float c2 = -2.12194440e-4f;
  const float p0 = 1.9875691500E-4f;
  const float p1 = 1.3981999507E-3f;
  const float p2 = 8.3334519073E-3f;
  const float p3 = 4.1665795894E-2f;
  const float p4 = 1.6666665459E-1f;
  const float p5 = 5.0000001201E-1f;
  float xc = fmaxf(x, exp_lo);
  float fx = floorf(xc * log2ef + 0.5f);
  float tmp = c1 * fx;
  float z = c2 * fx;
  float xx = xc - tmp;
  xx = xx - z;
  z = xx * xx;
  float y = xx * p0 + p1;
  y = y * xx + p2;
  y = y * xx + p3;
  y = y * xx + p4;
  y = y * xx + p5;
  y = y * z + xx;
  y = y + 1.0f;
  int ei = (int)fx;
  float s = __int_as_float((ei + 127) << 23);
  return y * s;
}

// ---------------- XLA:CPU log, trimmed for x in [1,2] ----------------
__device__ __forceinline__ float xla_log_12(float xin) {
  const float sqrthf = 0.707106781186547524f;
  const float p0 = 7.0376836292E-2f;
  const float p1 = -1.1514610310E-1f;
  const float p2 = 1.1676998740E-1f;
  const float p3 = -1.2420140846E-1f;
  const float p4 = 1.4249322787E-1f;
  const float p5 = -1.6668057665E-1f;
  const float p6 = 2.0000714765E-1f;
  const float p7 = -2.4999993993E-1f;
  const float p8 = 3.3333331174E-1f;
  const float q1 = -2.12194440e-4f;
  const float q2 = 0.693359375f;
  float x = xin;
  unsigned ub = __float_as_uint(x);
  int emm0 = (int)(ub >> 23) - 0x7f;
  float e = 1.0f + (float)emm0;
  x = __uint_as_float((ub & 0x007fffffu) | 0x3f000000u);
  bool mlt = x < sqrthf;
  float tmp = mlt ? x : 0.0f;
  x = x - 1.0f;
  e = e - (mlt ? 1.0f : 0.0f);
  x = x + tmp;
  float x2 = x * x;
  float x3 = x2 * x;
  float y  = x * p0 + p1;
  float y1 = x * p3 + p4;
  float y2 = x * p6 + p7;
  y  = y * x + p2;
  y1 = y1 * x + p5;
  y2 = y2 * x + p8;
  y = y * x3 + y1;
  y = y * x3 + y2;
  y = y * x3;
  y1 = q1 * e;
  float t2 = 0.5f * x2;
  y = y + y1;
  x = x - t2;
  y2 = q2 * e;
  x = x + y;
  x = x + y2;
  return x;
}

// XLA elemental log1p for e in [0,1]
__device__ __forceinline__ float xla_log1p_01(float x) {
  float fsmall = ((-0.5f * x) + 1.0f) * x;
  float flarge = xla_log_12(x + 1.0f);
  return (fabsf(x) < 1e-4f) ? fsmall : flarge;
}

// jnp.logaddexp, exact bits
__device__ __forceinline__ float xla_logaddexp(float a, float b) {
  float mx = fmaxf(a, b);
  float d = a - b;
  float e = xla_exp_neg(-fabsf(d));
  return mx + xla_log1p_01(e);
}

// Fast path (2e-2 tolerance consumers only: marginals).
__device__ __forceinline__ float fast_la(float a, float b) {
  float mx = fmaxf(a, b);
  float d = a - b;
  float e = __expf(-fabsf(d));
  return mx + __logf(1.0f + e);
}

// Full-wave shift-right-by-1 via DPP (wave_shr:1 = 0x138). Lane 0 <- fill.
__device__ __forceinline__ float dpp_shr1(float x, float fill) {
  int r = __builtin_amdgcn_update_dpp(__float_as_int(fill), __float_as_int(x),
                                      0x138, 0xF, 0xF, false);
  return __int_as_float(r);
}

__device__ __forceinline__ float readlane_f(float v, int l) {
  return __int_as_float(__builtin_amdgcn_readlane(__float_as_int(v), l));
}

// ---------------- Threefry-2x32, key = (0, 42), 20 rounds ----------------
__device__ __forceinline__ unsigned rotl_(unsigned v, int r) {
  return (v << r) | (v >> (32 - r));
}

__device__ __forceinline__ void threefry_0_42(unsigned c0, unsigned c1,
                                              unsigned* o0, unsigned* o1) {
  const unsigned ks0 = 0u, ks1 = 42u, ks2 = 0x1BD11BDAu ^ 0u ^ 42u;
  unsigned x0 = c0 + ks0, x1 = c1 + ks1;
  x0 += x1; x1 = rotl_(x1, 13); x1 ^= x0;
  x0 += x1; x1 = rotl_(x1, 15); x1 ^= x0;
  x0 += x1; x1 = rotl_(x1, 26); x1 ^= x0;
  x0 += x1; x1 = rotl_(x1, 6);  x1 ^= x0;
  x0 += ks1; x1 += ks2 + 1u;
  x0 += x1; x1 = rotl_(x1, 17); x1 ^= x0;
  x0 += x1; x1 = rotl_(x1, 29); x1 ^= x0;
  x0 += x1; x1 = rotl_(x1, 16); x1 ^= x0;
  x0 += x1; x1 = rotl_(x1, 24); x1 ^= x0;
  x0 += ks2; x1 += ks0 + 2u;
  x0 += x1; x1 = rotl_(x1, 13); x1 ^= x0;
  x0 += x1; x1 = rotl_(x1, 15); x1 ^= x0;
  x0 += x1; x1 = rotl_(x1, 26); x1 ^= x0;
  x0 += x1; x1 = rotl_(x1, 6);  x1 ^= x0;
  x0 += ks0; x1 += ks1 + 3u;
  x0 += x1; x1 = rotl_(x1, 17); x1 ^= x0;
  x0 += x1; x1 = rotl_(x1, 29); x1 ^= x0;
  x0 += x1; x1 = rotl_(x1, 16); x1 ^= x0;
  x0 += x1; x1 = rotl_(x1, 24); x1 ^= x0;
  x0 += ks1; x1 += ks2 + 4u;
  x0 += x1; x1 = rotl_(x1, 13); x1 ^= x0;
  x0 += x1; x1 = rotl_(x1, 15); x1 ^= x0;
  x0 += x1; x1 = rotl_(x1, 26); x1 ^= x0;
  x0 += x1; x1 = rotl_(x1, 6);  x1 ^= x0;
  x0 += ks2; x1 += ks0 + 5u;
  *o0 = x0; *o1 = x1;
}

__device__ __forceinline__ float u01_from_idx(unsigned idx) {
  unsigned b0, b1;
  threefry_0_42(0u, idx, &b0, &b1);     // jax_threefry_partitionable
  unsigned bits = b0 ^ b1;
  unsigned fb = (bits >> 9) | 0x3f800000u;
  return __uint_as_float(fb) - 1.0f;
}

// XOR-swizzled 64x32 tile: conflict-free col-writes AND row-reads.
__device__ __forceinline__ int sw_idx(int row, int col) {
  return row * 32 + ((col + row) & 31);
}

// ---------------- main kernel: one block (4 waves) per row b = bi*2 + ens ----------------
__global__ __launch_bounds__(256)
void EdgeSIMPLEBatched_39298950758997_kernel(const float* __restrict__ scores,
                                             float* __restrict__ out) {
  __shared__ float th_lds[N_C];          // 16384 B
  __shared__ float chkB[64 * 32];        // 8192 B: chkB[c] = exact B-row 64(c+1)
  __shared__ float chkF[63 * 32];        // 8064 B: chkF[c-1] = F-state at chunk c
  __shared__ float wtile[2][64 * 32];    // 16384 B: worker tiles (waves 1,3)
  __shared__ float ring[2][32 * 64];     // 16384 B: logq handoff ring
  __shared__ float logZ_s;
  __shared__ int   bReady;               // lowest chkB index published (desc)
  __shared__ int   fReady;               // highest chunk whose chkF is ready (asc)
  __shared__ int   claimIdx;             // phase-2 chunk claim counter
  __shared__ int   ringProd;             // groups produced into ring
  __shared__ int   consDone;             // groups consumed from ring

  const int t = threadIdx.x;
  const int w = t >> 6;
  const int lane = t & 63;
  const int b = blockIdx.x;
  const int bi = b >> 1, ens = b & 1;
  const float* srow = scores + bi * (N_C * 2) + ens;
  const int obase = bi * (N_C * 2) + ens;
  const int l31 = lane & 31;

  // ---- Phase 0: stage theta; init flags ----
  for (int idx = t; idx < N_C; idx += 256) th_lds[idx] = srow[idx * 2];
  if (t == 0) { bReady = 64; fReady = 0; claimIdx = 0; ringProd = 0; consDone = 0; }
  __syncthreads();

  if (w == 0) {
    // PRODUCER: bare exact backward B chain. Only per-step extras: one ds_write
    // of logq (fire-and-forget) — mask/threefry/ballot all offloaded to wave 2.
    float E = (lane == 0) ? 0.0f : NEG_C;
    if (lane < 32) chkB[63 * 32 + lane] = E;     // B-row 4096 = init
    __threadfence_block();
    if (lane == 0) *(volatile int*)&bReady = 63;
    float thb = th_lds[N_C - 1 - l31];
#pragma unroll 1
    for (int g = 0; g < 128; ++g) {
      const int nb = (g + 1 < 128) ? g + 1 : g;
      float thb_n = th_lds[N_C - 1 - nb * 32 - l31];
      if (g >= 2) {      // slot free when batch g-2 consumed
        volatile int* cd = &consDone;
        while (*cd < g - 1) __builtin_amdgcn_s_sleep(1);
      }
      float* rg = ring[g & 1];
#pragma unroll 4
      for (int l = 0; l < 32; ++l) {
        float th = readlane_f(thb, l);           // wave-uniform, off-chain
        float Em1 = dpp_shr1(E, NEG_C);          // B[i+1][j-1]
        float sh = Em1 + th;
        float Enew = xla_logaddexp(E, sh);       // EXACT chain
        rg[l * 64 + lane] = sh - Enew;           // logq (== (th+Em1)-Enew bitwise)
        E = Enew;
      }
      __threadfence_block();                     // drain ring writes before flag
      if (lane == 0) *(volatile int*)&ringProd = g + 1;
      if ((g & 1) == 1 && g < 127) {             // checkpoint + watermark
        const int c = ((127 - g) >> 1) - 1;
        if (lane < 32) chkB[c * 32 + lane] = E;
        __threadfence_block();
        if (lane == 0) *(volatile int*)&bReady = c;
      }
      thb = thb_n;
    }
    if (lane == 32) logZ_s = E;                  // B[0][k]
    __threadfence_block();
    if (lane == 0) *(volatile int*)&bReady = 0;
  } else if (w == 2) {
    // MASK CONSUMER: threefry-u + exact q + predicate + transposed-word stash.
#pragma unroll 1
    for (int g = 0; g < 128; ++g) {
      float ubv = u01_from_idx((unsigned)((N_C - 1 - g * 32 - l31) * BE_C + b));
      { volatile int* rp = &ringProd;
        while (*rp < g + 1) __builtin_amdgcn_s_sleep(1); }
      float* rg = ring[g & 1];
      unsigned Wbits = 0u;
#pragma unroll 8
      for (int l = 0; l < 32; ++l) {
        float logq = rg[l * 64 + lane];
        float u = readlane_f(ubv, l);
        float q = xla_exp_neg(fminf(logq, 0.0f));    // exact, ref op order
        Wbits |= ((u < q) ? 1u : 0u) << l;           // bit l <-> i = 4095-32g-l
      }
      if (lane >= 1 && lane <= 32)
        out[obase + ((127 - g) * 32 + lane - 1) * 2] = __uint_as_float(Wbits);
      __threadfence_block();                     // ring reads done before freeing slot
      if (lane == 0) *(volatile int*)&consDone = g + 1;
    }
  } else if (w == 1) {
    // Fast forward F scan, checkpoint + watermark every 64 rows.
    float F = (lane == 0) ? 0.0f : NEG_C;
    float th = th_lds[0];
#pragma unroll 2
    for (int i = 0; i < N_C; ++i) {
      float th_nx = th_lds[(i + 1 < N_C) ? i + 1 : i];
      if ((i & 63) == 0 && i > 0) {
        if (lane < 32) chkF[((i >> 6) - 1) * 32 + lane] = F;
        __threadfence_block();
        if (lane == 0) *(volatile int*)&fReady = (i >> 6);
      }
      float Fm1 = dpp_shr1(F, NEG_C);
      F = fast_la(F, Fm1 + th);
      th = th_nx;
    }
  }

  // ---- Worker pool (waves 1 & 3): marginal chunks, desc-c, watermark-gated ----
  if (w == 1 || w == 3) {
    float* wb = wtile[(w == 1) ? 0 : 1];
    for (;;) {
      int idxv = 0;
      if (lane == 0) idxv = atomicAdd(&claimIdx, 1);
      idxv = __shfl(idxv, 0);
      if (idxv >= 64) break;
      const int c = 63 - idxv;
      while (*(volatile int*)&bReady > c) __builtin_amdgcn_s_sleep(2);
      while (*(volatile int*)&fReady < c) __builtin_amdgcn_s_sleep(2);
      // Regen B rows c*64+1 .. c*64+64 into wb (row ii holds B[c*64+ii+1]).
      float E2 = chkB[c * 32 + l31];
      if (lane < 32) wb[sw_idx(63, lane)] = E2;
#pragma unroll 1
      for (int ii = 63; ii >= 1; --ii) {
        float th = th_lds[c * 64 + ii];
        float Em1 = dpp_shr1(E2, NEG_C);
        E2 = fast_la(E2, Em1 + th);
        if (lane < 32) wb[sw_idx(ii - 1, lane)] = E2;
      }
      // Forward F over chunk; overwrite each consumed B row with comb = F + B.
      float F2;
      if (c == 0) F2 = (lane == 0) ? 0.0f : NEG_C;
      else        F2 = (lane < 32) ? chkF[(c - 1) * 32 + lane] : NEG_C;
      float th = th_lds[c * 64];
#pragma unroll 2
      for (int ii = 0; ii < 64; ++ii) {
        float th_nx = th_lds[c * 64 + ((ii + 1 < 64) ? ii + 1 : ii)];
        float bbv = wb[sw_idx(ii, (31 - lane) & 31)];   // B[i+1][31-j]
        float comb = F2 + bbv;                          // F[i][j] + B[i+1][k-1-j]
        if (lane < 32) wb[sw_idx(ii, lane)] = comb;
        float Fm1 = dpp_shr1(F2, NEG_C);
        F2 = fast_la(F2, Fm1 + th);
        th = th_nx;
      }
      __threadfence_block();
      // Per-lane logsumexp of own comb row; store mraw (logZ applied later).
      float cb[32];
#pragma unroll
      for (int jj = 0; jj < 32; ++jj) cb[jj] = wb[sw_idx(lane, jj)];
      float amax = cb[0];
#pragma unroll
      for (int jj = 1; jj < 32; ++jj) amax = fmaxf(amax, cb[jj]);
      float ss = 0.0f;
#pragma unroll
      for (int jj = 0; jj < 32; ++jj) ss += __expf(cb[jj] - amax);
      float thi = th_lds[c * 64 + lane];
      float mraw = thi + (__logf(ss) + amax);
      out[OUT_HALF + obase + (c * 64 + lane) * 2] = mraw;
    }
  }
  __syncthreads();

  // ---- Finalize marginals: m = exp(mraw - logZ) ----
  {
    const float logZ = logZ_s;
    for (int idx = t; idx < N_C; idx += 256) {
      const int o = OUT_HALF + obase + idx * 2;
      out[o] = __expf(out[o] - logZ);
    }
  }
  __syncthreads();

  // ---- Phase 3: sequential conditional-Poisson walk (wave 0), bit-exact ----
  if (w == 0) {
    int r = K_C;
    unsigned Wv = 0u;
    if (lane >= 1 && lane <= 32)
      Wv = __float_as_uint(out[obase + (lane - 1) * 2]);     // group 127
#pragma unroll 1
    for (int g = 127; g >= 0; --g) {
      unsigned Wn = 0u;
      if (g > 0 && lane >= 1 && lane <= 32)
        Wn = __float_as_uint(out[obase + ((128 - g) * 32 + lane - 1) * 2]);
      const int i_l = N_C - 1 - 32 * g - l31;
      float mval = out[OUT_HALF + obase + i_l * 2];
      unsigned inclW = 0u;
#pragma unroll 8
      for (int l = 31; l >= 0; --l) {              // i ascending within group
        unsigned mm = (unsigned)__builtin_amdgcn_readlane((int)Wv, r);
        unsigned bit = (mm >> l) & 1u;
        inclW |= bit << l;
        r -= (int)bit;
      }
      if (lane < 32) {
        unsigned incl = (inclW >> l31) & 1u;
        float sval = incl ? ((1.0f - mval) + mval) : 0.0f;   // (s-m)+m
        out[obase + i_l * 2] = sval;
      }
      Wv = Wn;
    }
  }
}

extern "C" void kernel_launch(void* const* d_in, const int* in_sizes, int n_in,
                              void* d_out, int out_size, void* d_ws, size_t ws_size,
                              hipStream_t stream) {
  (void)in_sizes; (void)n_in; (void)d_ws; (void)ws_size; (void)out_size;
  const float* scores = (const float*)d_in[0];
  float* out = (float*)d_out;
  EdgeSIMPLEBatched_39298950758997_kernel<<<dim3(BE_C), dim3(256), 0, stream>>>(scores, out);
}

// Round 8
// 1016.804 us; speedup vs baseline: 1.0280x; 1.0280x over previous
//
#include <hip/hip_runtime.h>
#include <stdint.h>

// Keep mul+add sequences UNFUSED so we bit-match XLA:CPU's unfused MulAdd ops.
#pragma clang fp contract(off)

#define BE_C     256
#define N_C      4096
#define K_C      32
#define NEG_C    (-1e30f)
#define OUT_HALF 1048576

// ---------------- XLA:CPU exp, trimmed for x <= 0 (bit-exact identities) ----------------
__device__ __forceinline__ float xla_exp_neg(float x) {
  const float exp_lo = -88.3762626647949f;
  const float log2ef = 1.44269504088896341f;
  const float c1 = 0.693359375f;
  const float c2 = -2.12194440e-4f;
  const float p0 = 1.9875691500E-4f;
  const float p1 = 1.3981999507E-3f;
  const float p2 = 8.3334519073E-3f;
  const float p3 = 4.1665795894E-2f;
  const float p4 = 1.6666665459E-1f;
  const float p5 = 5.0000001201E-1f;
  float xc = fmaxf(x, exp_lo);
  float fx = floorf(xc * log2ef + 0.5f);
  float tmp = c1 * fx;
  float z = c2 * fx;
  float xx = xc - tmp;
  xx = xx - z;
  z = xx * xx;
  float y = xx * p0 + p1;
  y = y * xx + p2;
  y = y * xx + p3;
  y = y * xx + p4;
  y = y * xx + p5;
  y = y * z + xx;
  y = y + 1.0f;
  int ei = (int)fx;
  float s = __int_as_float((ei + 127) << 23);
  return y * s;
}

// ---------------- XLA:CPU log, trimmed for x in [1,2] ----------------
__device__ __forceinline__ float xla_log_12(float xin) {
  const float sqrthf = 0.707106781186547524f;
  const float p0 = 7.0376836292E-2f;
  const float p1 = -1.1514610310E-1f;
  const float p2 = 1.1676998740E-1f;
  const float p3 = -1.2420140846E-1f;
  const float p4 = 1.4249322787E-1f;
  const float p5 = -1.6668057665E-1f;
  const float p6 = 2.0000714765E-1f;
  const float p7 = -2.4999993993E-1f;
  const float p8 = 3.3333331174E-1f;
  const float q1 = -2.12194440e-4f;
  const float q2 = 0.693359375f;
  float x = xin;
  unsigned ub = __float_as_uint(x);
  int emm0 = (int)(ub >> 23) - 0x7f;
  float e = 1.0f + (float)emm0;
  x = __uint_as_float((ub & 0x007fffffu) | 0x3f000000u);
  bool mlt = x < sqrthf;
  float tmp = mlt ? x : 0.0f;
  x = x - 1.0f;
  e = e - (mlt ? 1.0f : 0.0f);
  x = x + tmp;
  float x2 = x * x;
  float x3 = x2 * x;
  float y  = x * p0 + p1;
  float y1 = x * p3 + p4;
  float y2 = x * p6 + p7;
  y  = y * x + p2;
  y1 = y1 * x + p5;
  y2 = y2 * x + p8;
  y = y * x3 + y1;
  y = y * x3 + y2;
  y = y * x3;
  y1 = q1 * e;
  float t2 = 0.5f * x2;
  y = y + y1;
  x = x - t2;
  y2 = q2 * e;
  x = x + y;
  x = x + y2;
  return x;
}

// XLA elemental log1p for e in [0,1]
__device__ __forceinline__ float xla_log1p_01(float x) {
  float fsmall = ((-0.5f * x) + 1.0f) * x;
  float flarge = xla_log_12(x + 1.0f);
  return (fabsf(x) < 1e-4f) ? fsmall : flarge;
}

// jnp.logaddexp, exact bits
__device__ __forceinline__ float xla_logaddexp(float a, float b) {
  float mx = fmaxf(a, b);
  float d = a - b;
  float e = xla_exp_neg(-fabsf(d));
  return mx + xla_log1p_01(e);
}

// Fast path (2e-2 tolerance consumers only: marginals).
__device__ __forceinline__ float fast_la(float a, float b) {
  float mx = fmaxf(a, b);
  float d = a - b;
  float e = __expf(-fabsf(d));
  return mx + __logf(1.0f + e);
}

// Full-wave shift-right-by-1 via DPP (wave_shr:1 = 0x138). Lane 0 <- fill.
__device__ __forceinline__ float dpp_shr1(float x, float fill) {
  int r = __builtin_amdgcn_update_dpp(__float_as_int(fill), __float_as_int(x),
                                      0x138, 0xF, 0xF, false);
  return __int_as_float(r);
}

__device__ __forceinline__ float readlane_f(float v, int l) {
  return __int_as_float(__builtin_amdgcn_readlane(__float_as_int(v), l));
}

// ---------------- Threefry-2x32, key = (0, 42), 20 rounds ----------------
__device__ __forceinline__ unsigned rotl_(unsigned v, int r) {
  return (v << r) | (v >> (32 - r));
}

__device__ __forceinline__ void threefry_0_42(unsigned c0, unsigned c1,
                                              unsigned* o0, unsigned* o1) {
  const unsigned ks0 = 0u, ks1 = 42u, ks2 = 0x1BD11BDAu ^ 0u ^ 42u;
  unsigned x0 = c0 + ks0, x1 = c1 + ks1;
  x0 += x1; x1 = rotl_(x1, 13); x1 ^= x0;
  x0 += x1; x1 = rotl_(x1, 15); x1 ^= x0;
  x0 += x1; x1 = rotl_(x1, 26); x1 ^= x0;
  x0 += x1; x1 = rotl_(x1, 6);  x1 ^= x0;
  x0 += ks1; x1 += ks2 + 1u;
  x0 += x1; x1 = rotl_(x1, 17); x1 ^= x0;
  x0 += x1; x1 = rotl_(x1, 29); x1 ^= x0;
  x0 += x1; x1 = rotl_(x1, 16); x1 ^= x0;
  x0 += x1; x1 = rotl_(x1, 24); x1 ^= x0;
  x0 += ks2; x1 += ks0 + 2u;
  x0 += x1; x1 = rotl_(x1, 13); x1 ^= x0;
  x0 += x1; x1 = rotl_(x1, 15); x1 ^= x0;
  x0 += x1; x1 = rotl_(x1, 26); x1 ^= x0;
  x0 += x1; x1 = rotl_(x1, 6);  x1 ^= x0;
  x0 += ks0; x1 += ks1 + 3u;
  x0 += x1; x1 = rotl_(x1, 17); x1 ^= x0;
  x0 += x1; x1 = rotl_(x1, 29); x1 ^= x0;
  x0 += x1; x1 = rotl_(x1, 16); x1 ^= x0;
  x0 += x1; x1 = rotl_(x1, 24); x1 ^= x0;
  x0 += ks1; x1 += ks2 + 4u;
  x0 += x1; x1 = rotl_(x1, 13); x1 ^= x0;
  x0 += x1; x1 = rotl_(x1, 15); x1 ^= x0;
  x0 += x1; x1 = rotl_(x1, 26); x1 ^= x0;
  x0 += x1; x1 = rotl_(x1, 6);  x1 ^= x0;
  x0 += ks2; x1 += ks0 + 5u;
  *o0 = x0; *o1 = x1;
}

__device__ __forceinline__ float u01_from_idx(unsigned idx) {
  unsigned b0, b1;
  threefry_0_42(0u, idx, &b0, &b1);     // jax_threefry_partitionable
  unsigned bits = b0 ^ b1;
  unsigned fb = (bits >> 9) | 0x3f800000u;
  return __uint_as_float(fb) - 1.0f;
}

// XOR-swizzled 64x32 tile: conflict-free col-writes AND row-reads.
__device__ __forceinline__ int sw_idx(int row, int col) {
  return row * 32 + ((col + row) & 31);
}

// ---------------- main kernel: one block (4 waves) per row b = bi*2 + ens ----------------
__global__ __launch_bounds__(256)
void EdgeSIMPLEBatched_39298950758997_kernel(const float* __restrict__ scores,
                                             float* __restrict__ out) {
  __shared__ float th_lds[N_C];          // 16384 B
  __shared__ float chkB[64 * 32];        // 8192 B: chkB[c] = exact B-row 64(c+1)
  __shared__ float chkF[63 * 32];        // 8064 B: chkF[c-1] = F-state at chunk c
  __shared__ float wbuf[4][64 * 32];     // 32768 B: per-wave tile
  __shared__ float logZ_s;
  __shared__ int   bReady;               // lowest chkB index published (desc)
  __shared__ int   fReady;               // highest chunk whose chkF is ready (asc)
  __shared__ int   claimIdx;             // phase-2 chunk claim counter

  const int t = threadIdx.x;
  const int w = t >> 6;
  const int lane = t & 63;
  const int b = blockIdx.x;
  const int bi = b >> 1, ens = b & 1;
  const float* srow = scores + bi * (N_C * 2) + ens;
  const int obase = bi * (N_C * 2) + ens;
  const int l31 = lane & 31;

  // ---- Phase 0: stage theta; init flags ----
  for (int idx = t; idx < N_C; idx += 256) th_lds[idx] = srow[idx * 2];
  if (t == 0) { bReady = 64; fReady = 0; claimIdx = 0; }
  __syncthreads();

  // ---- Phase 1 (roles) + overlapped phase 2 (worker pool) ----
  if (w == 0) {
    // PRODUCER: exact backward B chain + inline masks + chkB watermarks.
    float E = (lane == 0) ? 0.0f : NEG_C;
    if (lane < 32) chkB[63 * 32 + lane] = E;     // B-row 4096 = init
    __threadfence_block();
    if (lane == 0) *(volatile int*)&bReady = 63;
    float thb = th_lds[N_C - 1 - l31];
    float ub  = u01_from_idx((unsigned)((N_C - 1 - l31) * BE_C + b));
    unsigned Wbits = 0u;
#pragma unroll 1
    for (int g = 0; g < 128; ++g) {
      const int nb = (g + 1 < 128) ? g + 1 : g;  // prefetch next group (dbuf)
      float thb_n = th_lds[N_C - 1 - nb * 32 - l31];
      float ub_n  = u01_from_idx((unsigned)((N_C - 1 - nb * 32 - l31) * BE_C + b));
#pragma unroll 4
      for (int l = 0; l < 32; ++l) {
        float th = readlane_f(thb, l);           // wave-uniform, off-chain
        float u  = readlane_f(ub, l);
        float Em1 = dpp_shr1(E, NEG_C);          // B[i+1][j-1]
        float sh = Em1 + th;
        float Enew = xla_logaddexp(E, sh);       // EXACT chain
        float logq = (th + Em1) - Enew;          // exact, ref op order
        float q = xla_exp_neg(fminf(logq, 0.0f));// off-chain
        unsigned pb = (u < q) ? 1u : 0u;
        Wbits |= pb << l;                        // bit l <-> i = 4095 - 32g - l
        E = Enew;
      }
      if (lane >= 1 && lane <= 32)               // transposed mask stash
        out[obase + ((127 - g) * 32 + lane - 1) * 2] = __uint_as_float(Wbits);
      Wbits = 0u;
      if ((g & 1) == 1 && g < 127) {             // checkpoint + watermark
        const int c = ((127 - g) >> 1) - 1;
        if (lane < 32) chkB[c * 32 + lane] = E;
        __threadfence_block();
        if (lane == 0) *(volatile int*)&bReady = c;
      }
      thb = thb_n; ub = ub_n;
    }
    if (lane == 32) logZ_s = E;                  // B[0][k]
    __threadfence_block();
    if (lane == 0) *(volatile int*)&bReady = 0;
  } else if (w == 1) {
    // Fast forward F scan, checkpoint + watermark every 64 rows.
    float F = (lane == 0) ? 0.0f : NEG_C;
    float th = th_lds[0];
#pragma unroll 2
    for (int i = 0; i < N_C; ++i) {
      float th_nx = th_lds[(i + 1 < N_C) ? i + 1 : i];
      if ((i & 63) == 0 && i > 0) {
        if (lane < 32) chkF[((i >> 6) - 1) * 32 + lane] = F;
        __threadfence_block();
        if (lane == 0) *(volatile int*)&fReady = (i >> 6);
      }
      float Fm1 = dpp_shr1(F, NEG_C);
      F = fast_la(F, Fm1 + th);
      th = th_nx;
    }
  }

  // ---- Worker pool (all waves join as they free up): marginal chunks ----
  {
    float* wb = wbuf[w];
    for (;;) {
      int idxv = 0;
      if (lane == 0) idxv = atomicAdd(&claimIdx, 1);
      idxv = __shfl(idxv, 0);
      if (idxv >= 64) break;
      const int c = 63 - idxv;
      while (*(volatile int*)&bReady > c) __builtin_amdgcn_s_sleep(2);
      while (*(volatile int*)&fReady < c) __builtin_amdgcn_s_sleep(2);
      // Regen B rows c*64+1 .. c*64+64 into wb (row ii holds B[c*64+ii+1]).
      float E2 = chkB[c * 32 + l31];
      if (lane < 32) wb[sw_idx(63, lane)] = E2;
#pragma unroll 1
      for (int ii = 63; ii >= 1; --ii) {
        float th = th_lds[c * 64 + ii];
        float Em1 = dpp_shr1(E2, NEG_C);
        E2 = fast_la(E2, Em1 + th);
        if (lane < 32) wb[sw_idx(ii - 1, lane)] = E2;
      }
      // Forward F over chunk; overwrite each consumed B row with comb = F + B.
      float F2;
      if (c == 0) F2 = (lane == 0) ? 0.0f : NEG_C;
      else        F2 = (lane < 32) ? chkF[(c - 1) * 32 + lane] : NEG_C;
      float th = th_lds[c * 64];
#pragma unroll 2
      for (int ii = 0; ii < 64; ++ii) {
        float th_nx = th_lds[c * 64 + ((ii + 1 < 64) ? ii + 1 : ii)];
        float bbv = wb[sw_idx(ii, (31 - lane) & 31)];   // B[i+1][31-j]
        float comb = F2 + bbv;                          // F[i][j] + B[i+1][k-1-j]
        if (lane < 32) wb[sw_idx(ii, lane)] = comb;
        float Fm1 = dpp_shr1(F2, NEG_C);
        F2 = fast_la(F2, Fm1 + th);
        th = th_nx;
      }
      __threadfence_block();
      // Per-lane logsumexp of own comb row; store mraw (logZ applied in walk).
      float cb[32];
#pragma unroll
      for (int jj = 0; jj < 32; ++jj) cb[jj] = wb[sw_idx(lane, jj)];
      float amax = cb[0];
#pragma unroll
      for (int jj = 1; jj < 32; ++jj) amax = fmaxf(amax, cb[jj]);
      float ss = 0.0f;
#pragma unroll
      for (int jj = 0; jj < 32; ++jj) ss += __expf(cb[jj] - amax);
      float thi = th_lds[c * 64 + lane];
      float mraw = thi + (__logf(ss) + amax);
      out[OUT_HALF + obase + (c * 64 + lane) * 2] = mraw;
    }
  }
  __syncthreads();

  // ---- Phase 3 (wave 0): sampling walk fused with marginal finalize ----
  if (w == 0) {
    const float logZ = logZ_s;
    int r = K_C;
    unsigned Wv = 0u;
    if (lane >= 1 && lane <= 32)
      Wv = __float_as_uint(out[obase + (lane - 1) * 2]);     // group 127
#pragma unroll 1
    for (int g = 127; g >= 0; --g) {
      unsigned Wn = 0u;
      if (g > 0 && lane >= 1 && lane <= 32)
        Wn = __float_as_uint(out[obase + ((128 - g) * 32 + lane - 1) * 2]);
      const int i_l = N_C - 1 - 32 * g - l31;
      float mraw = out[OUT_HALF + obase + i_l * 2];
      float m = __expf(mraw - logZ);               // lane-parallel, off-chain
      unsigned inclW = 0u;
#pragma unroll 8
      for (int l = 31; l >= 0; --l) {              // i ascending within group
        unsigned mm = (unsigned)__builtin_amdgcn_readlane((int)Wv, r);
        unsigned bit = (mm >> l) & 1u;
        inclW |= bit << l;
        r -= (int)bit;
      }
      if (lane < 32) {
        unsigned incl = (inclW >> l31) & 1u;
        float sval = incl ? ((1.0f - m) + m) : 0.0f;   // (s-m)+m
        out[obase + i_l * 2] = sval;                   // sample
        out[OUT_HALF + obase + i_l * 2] = m;           // finalized marginal
      }
      Wv = Wn;
    }
  }
}

extern "C" void kernel_launch(void* const* d_in, const int* in_sizes, int n_in,
                              void* d_out, int out_size, void* d_ws, size_t ws_size,
                              hipStream_t stream) {
  (void)in_sizes; (void)n_in; (void)d_ws; (void)ws_size; (void)out_size;
  const float* scores = (const float*)d_in[0];
  float* out = (float*)d_out;
  EdgeSIMPLEBatched_39298950758997_kernel<<<dim3(BE_C), dim3(256), 0, stream>>>(scores, out);
}